// Round 7
// baseline (362.288 us; speedup 1.0000x reference)
//
#include <hip/hip_runtime.h>

// SSIM loss, fused. Round 7: LINEAR LDS layout (drop the stride-12 swizzle).
//  - r6 post-mortem: swizzle caused the 8.7M bank-conflict cycles (it was
//    designed for r2's 8px b128 reads). Linear layout analysis:
//      * float2 publish at word 2t: each 16-lane phase covers 32 banks
//        exactly once -> zero conflicts.
//      * reads b128@4ht, b128@4ht+4, b64@4ht+8: 2 lanes/bank -> free (m136).
//  - LDS 31.2 -> 20.8 KB: 7 blocks/CU = 28 waves resident (was 20).
//  - Everything else = r5/r6: 256 thr, float2 vertical ownership, 2 rows per
//    iteration, 4 px/thread horizontal, prefetched retire re-read, block
//    partials + reducing finalize.

#define IW    512
#define OUTW  506
#define BAND  22          // output rows per block; 22*23 = 506 exactly
#define NBANDS 23
#define NIMG  96
#define NPART (NBANDS * NIMG)   // 2208 block partials
#define PLW   520         // padded plane width in words (max read = 517)
#define C1N2  0.2401f     // 1e-4 * 49^2
#define C2N2  2.1609f     // 9e-4 * 49^2
#define KA    (49.0f/24.0f)
#define KB    (49.0f/48.0f)
#define TOTAL_OUT 24579456.0f   // 96*506*506

__device__ __forceinline__ float ssim_raw(float Sx, float Sy, float Sxx,
                                          float Syy, float Sxy) {
    float sxsy = Sx * Sy;
    float p    = fmaf(Sx, Sx, Sy * Sy);
    float a1   = fmaf(2.0f, sxsy, C1N2);
    float b1   = p + C1N2;
    float a2   = fmaf(KA, fmaf(49.0f, Sxy, -sxsy), C2N2);
    float b2   = fmaf(KB, fmaf(49.0f, Sxx + Syy, -p), C2N2);
    return (a1 * a2) * __builtin_amdgcn_rcpf(b1 * b2);
}

__global__ __launch_bounds__(256, 7) void ssim_main(const float* __restrict__ X,
                                                    const float* __restrict__ Y,
                                                    float* __restrict__ partials) {
    __shared__ float plane[2][5][PLW];   // linear: word c = column sum of col c
    __shared__ float wsum[4];

    const int t    = threadIdx.x;
    const int band = blockIdx.x;
    const int img  = blockIdx.y;
    const int r0   = band * BAND;
    const float2* X2 = (const float2*)(X + (size_t)img * IW * IW);
    const float2* Y2 = (const float2*)(Y + (size_t)img * IW * IW);

    float sxa=0,sxb=0, sya=0,syb=0, sxxa=0,sxxb=0, syya=0,syyb=0, sxya=0,sxyb=0;

#pragma unroll
    for (int i = 0; i < 6; ++i) {
        float2 x = X2[(r0 + i) * 256 + t];
        float2 y = Y2[(r0 + i) * 256 + t];
        sxa += x.x;  sxb += x.y;  sya += y.x;  syb += y.y;
        sxxa = fmaf(x.x,x.x,sxxa); sxxb = fmaf(x.y,x.y,sxxb);
        syya = fmaf(y.x,y.x,syya); syyb = fmaf(y.y,y.y,syyb);
        sxya = fmaf(x.x,y.x,sxya); sxyb = fmaf(x.y,y.y,sxyb);
    }

    const int woff = 2 * t;            // linear word offset of col 2t

    // horizontal mapping: 2 waves per row, thread -> 4 px
    const int hw = t >> 7;             // which of the 2 rows this iter
    const int ht = t & 127;
    const int p0 = 4 * ht;             // first output col (reads words p0..p0+9)

    // prefetch for j=0: new rows r0+6,r0+7; retire rows r0,r0+1
    float2 nx[2], ny[2], rx[2], ry[2];
#pragma unroll
    for (int k = 0; k < 2; ++k) {
        nx[k] = X2[(r0 + 6 + k) * 256 + t];
        ny[k] = Y2[(r0 + 6 + k) * 256 + t];
        rx[k] = X2[(r0 + k) * 256 + t];
        ry[k] = Y2[(r0 + k) * 256 + t];
    }

    float accS = 0.0f;

    for (int j = 0; j < BAND; j += 2) {
#pragma unroll
        for (int k = 0; k < 2; ++k) {
            // add new input row (prefetched) -> window rows [r0+j+k .. +6]
            float2 x = nx[k], y = ny[k];
            sxa += x.x;  sxb += x.y;  sya += y.x;  syb += y.y;
            sxxa = fmaf(x.x,x.x,sxxa); sxxb = fmaf(x.y,x.y,sxxb);
            syya = fmaf(y.x,y.x,syya); syyb = fmaf(y.y,y.y,syyb);
            sxya = fmaf(x.x,y.x,sxya); sxyb = fmaf(x.y,y.y,sxyb);
            // publish (linear, conflict-free)
            *(float2*)&plane[k][0][woff] = make_float2(sxa,  sxb);
            *(float2*)&plane[k][1][woff] = make_float2(sya,  syb);
            *(float2*)&plane[k][2][woff] = make_float2(sxxa, sxxb);
            *(float2*)&plane[k][3][woff] = make_float2(syya, syyb);
            *(float2*)&plane[k][4][woff] = make_float2(sxya, sxyb);
            // retire oldest row (prefetched)
            float2 ox = rx[k], oy = ry[k];
            sxa -= ox.x;  sxb -= ox.y;  sya -= oy.x;  syb -= oy.y;
            sxxa = fmaf(-ox.x,ox.x,sxxa); sxxb = fmaf(-ox.y,ox.y,sxxb);
            syya = fmaf(-oy.x,oy.x,syya); syyb = fmaf(-oy.y,oy.y,syyb);
            sxya = fmaf(-ox.x,oy.x,sxya); sxyb = fmaf(-ox.y,oy.y,sxyb);
        }
        // prefetch next iteration's rows
        if (j + 2 < BAND) {
#pragma unroll
            for (int k = 0; k < 2; ++k) {
                nx[k] = X2[(r0 + j + 8 + k) * 256 + t];
                ny[k] = Y2[(r0 + j + 8 + k) * 256 + t];
                rx[k] = X2[(r0 + j + 2 + k) * 256 + t];
                ry[k] = Y2[(r0 + j + 2 + k) * 256 + t];
            }
        }
        __syncthreads();   // column sums visible

        // horizontal: 4 px per thread on row (r0+j+hw), cols p0..p0+3
        {
            float c[5][10];
#pragma unroll
            for (int q = 0; q < 5; ++q) {
                const float* pl = plane[hw][q];
                float4 A = *(const float4*)(pl + p0);
                float4 B = *(const float4*)(pl + p0 + 4);
                float2 C = *(const float2*)(pl + p0 + 8);
                c[q][0]=A.x; c[q][1]=A.y; c[q][2]=A.z; c[q][3]=A.w;
                c[q][4]=B.x; c[q][5]=B.y; c[q][6]=B.z; c[q][7]=B.w;
                c[q][8]=C.x; c[q][9]=C.y;
            }
            float W[5];
#pragma unroll
            for (int q = 0; q < 5; ++q)
                W[q] = ((c[q][0] + c[q][1]) + (c[q][2] + c[q][3])) +
                       ((c[q][4] + c[q][5]) + c[q][6]);
            accS += (p0 < OUTW) ? ssim_raw(W[0],W[1],W[2],W[3],W[4]) : 0.0f;
#pragma unroll
            for (int m = 1; m < 4; ++m) {
#pragma unroll
                for (int q = 0; q < 5; ++q)
                    W[q] += c[q][m + 6] - c[q][m - 1];
                float Sv = ssim_raw(W[0],W[1],W[2],W[3],W[4]);
                accS += (p0 + m < OUTW) ? Sv : 0.0f;
            }
        }
        __syncthreads();   // reads done before next iteration's writes
    }

    // block reduce -> one partial per block (no atomics, no init needed)
#pragma unroll
    for (int o = 32; o > 0; o >>= 1)
        accS += __shfl_down(accS, o, 64);
    if ((t & 63) == 0) wsum[t >> 6] = accS;
    __syncthreads();
    if (t == 0)
        partials[blockIdx.y * NBANDS + blockIdx.x] =
            (wsum[0] + wsum[1]) + (wsum[2] + wsum[3]);
}

__global__ __launch_bounds__(256) void ssim_finalize(const float* __restrict__ partials,
                                                     float* __restrict__ out) {
    __shared__ float wsum[4];
    const int t = threadIdx.x;
    float v = 0.0f;
    for (int i = t; i < NPART; i += 256) v += partials[i];
#pragma unroll
    for (int o = 32; o > 0; o >>= 1)
        v += __shfl_down(v, o, 64);
    if ((t & 63) == 0) wsum[t >> 6] = v;
    __syncthreads();
    if (t == 0)
        out[0] = 1.0f - ((wsum[0] + wsum[1]) + (wsum[2] + wsum[3])) / TOTAL_OUT;
}

extern "C" void kernel_launch(void* const* d_in, const int* in_sizes, int n_in,
                              void* d_out, int out_size, void* d_ws, size_t ws_size,
                              hipStream_t stream) {
    const float* X = (const float*)d_in[0];
    const float* Y = (const float*)d_in[1];
    float* partials = (float*)d_ws;          // NPART floats (8.8 KB)
    float* out = (float*)d_out;

    hipLaunchKernelGGL(ssim_main, dim3(NBANDS, NIMG), dim3(256), 0, stream,
                       X, Y, partials);
    hipLaunchKernelGGL(ssim_finalize, dim3(1), dim3(256), 0, stream,
                       partials, out);
}

// Round 8
// 227.183 us; speedup vs baseline: 1.5947x; 1.5947x over previous
//
#include <hip/hip_runtime.h>

// SSIM loss, fused. Round 8: r7 linear layout + r5's launch bounds (NO spill).
//  - r7 post-mortem: (256,7) capped VGPR at 36 -> prefetch + window arrays
//    spilled to scratch = 360 MB HBM writes/reads, 90->226 µs. The linear
//    layout itself was validated: conflicts 8.74M -> 0.97M, occupancy 64%.
//  - This round: linear LDS (20.5 KB, 7 blocks/CU = 28 waves) with
//    __launch_bounds__(256,5) -> 48 VGPR, zero scratch.
//  - Data path unchanged from r5-r7: float2 vertical ownership, 2 rows/iter,
//    4 px/thread horizontal, prefetched retire re-read, block partials.

#define IW    512
#define OUTW  506
#define BAND  22          // output rows per block; 22*23 = 506 exactly
#define NBANDS 23
#define NIMG  96
#define NPART (NBANDS * NIMG)   // 2208 block partials
#define PLW   520         // plane width in words (max read word = 517)
#define C1N2  0.2401f     // 1e-4 * 49^2
#define C2N2  2.1609f     // 9e-4 * 49^2
#define KA    (49.0f/24.0f)
#define KB    (49.0f/48.0f)
#define TOTAL_OUT 24579456.0f   // 96*506*506

__device__ __forceinline__ float ssim_raw(float Sx, float Sy, float Sxx,
                                          float Syy, float Sxy) {
    float sxsy = Sx * Sy;
    float p    = fmaf(Sx, Sx, Sy * Sy);
    float a1   = fmaf(2.0f, sxsy, C1N2);
    float b1   = p + C1N2;
    float a2   = fmaf(KA, fmaf(49.0f, Sxy, -sxsy), C2N2);
    float b2   = fmaf(KB, fmaf(49.0f, Sxx + Syy, -p), C2N2);
    return (a1 * a2) * __builtin_amdgcn_rcpf(b1 * b2);
}

__global__ __launch_bounds__(256, 5) void ssim_main(const float* __restrict__ X,
                                                    const float* __restrict__ Y,
                                                    float* __restrict__ partials) {
    __shared__ float plane[2][5][PLW];   // linear: word c = column sum, col c
    __shared__ float wsum[4];

    const int t    = threadIdx.x;
    const int band = blockIdx.x;
    const int img  = blockIdx.y;
    const int r0   = band * BAND;
    const float2* X2 = (const float2*)(X + (size_t)img * IW * IW);
    const float2* Y2 = (const float2*)(Y + (size_t)img * IW * IW);

    float sxa=0,sxb=0, sya=0,syb=0, sxxa=0,sxxb=0, syya=0,syyb=0, sxya=0,sxyb=0;

#pragma unroll
    for (int i = 0; i < 6; ++i) {
        float2 x = X2[(r0 + i) * 256 + t];
        float2 y = Y2[(r0 + i) * 256 + t];
        sxa += x.x;  sxb += x.y;  sya += y.x;  syb += y.y;
        sxxa = fmaf(x.x,x.x,sxxa); sxxb = fmaf(x.y,x.y,sxxb);
        syya = fmaf(y.x,y.x,syya); syyb = fmaf(y.y,y.y,syyb);
        sxya = fmaf(x.x,y.x,sxya); sxyb = fmaf(x.y,y.y,sxyb);
    }

    const int woff = 2 * t;            // linear word offset of col 2t

    // horizontal mapping: 2 waves per row, thread -> 4 px
    const int hw = t >> 7;             // which of the 2 rows this iter
    const int ht = t & 127;
    const int p0 = 4 * ht;             // first output col (reads words p0..p0+9)

    // prefetch for j=0: new rows r0+6,r0+7; retire rows r0,r0+1
    float2 nx[2], ny[2], rx[2], ry[2];
#pragma unroll
    for (int k = 0; k < 2; ++k) {
        nx[k] = X2[(r0 + 6 + k) * 256 + t];
        ny[k] = Y2[(r0 + 6 + k) * 256 + t];
        rx[k] = X2[(r0 + k) * 256 + t];
        ry[k] = Y2[(r0 + k) * 256 + t];
    }

    float accS = 0.0f;

    for (int j = 0; j < BAND; j += 2) {
#pragma unroll
        for (int k = 0; k < 2; ++k) {
            // add new input row (prefetched) -> window rows [r0+j+k .. +6]
            float2 x = nx[k], y = ny[k];
            sxa += x.x;  sxb += x.y;  sya += y.x;  syb += y.y;
            sxxa = fmaf(x.x,x.x,sxxa); sxxb = fmaf(x.y,x.y,sxxb);
            syya = fmaf(y.x,y.x,syya); syyb = fmaf(y.y,y.y,syyb);
            sxya = fmaf(x.x,y.x,sxya); sxyb = fmaf(x.y,y.y,sxyb);
            // publish (linear, conflict-free)
            *(float2*)&plane[k][0][woff] = make_float2(sxa,  sxb);
            *(float2*)&plane[k][1][woff] = make_float2(sya,  syb);
            *(float2*)&plane[k][2][woff] = make_float2(sxxa, sxxb);
            *(float2*)&plane[k][3][woff] = make_float2(syya, syyb);
            *(float2*)&plane[k][4][woff] = make_float2(sxya, sxyb);
            // retire oldest row (prefetched)
            float2 ox = rx[k], oy = ry[k];
            sxa -= ox.x;  sxb -= ox.y;  sya -= oy.x;  syb -= oy.y;
            sxxa = fmaf(-ox.x,ox.x,sxxa); sxxb = fmaf(-ox.y,ox.y,sxxb);
            syya = fmaf(-oy.x,oy.x,syya); syyb = fmaf(-oy.y,oy.y,syyb);
            sxya = fmaf(-ox.x,oy.x,sxya); sxyb = fmaf(-ox.y,oy.y,sxyb);
        }
        // prefetch next iteration's rows
        if (j + 2 < BAND) {
#pragma unroll
            for (int k = 0; k < 2; ++k) {
                nx[k] = X2[(r0 + j + 8 + k) * 256 + t];
                ny[k] = Y2[(r0 + j + 8 + k) * 256 + t];
                rx[k] = X2[(r0 + j + 2 + k) * 256 + t];
                ry[k] = Y2[(r0 + j + 2 + k) * 256 + t];
            }
        }
        __syncthreads();   // column sums visible

        // horizontal: 4 px per thread on row (r0+j+hw), cols p0..p0+3
        {
            float c[5][10];
#pragma unroll
            for (int q = 0; q < 5; ++q) {
                const float* pl = plane[hw][q];
                float4 A = *(const float4*)(pl + p0);
                float4 B = *(const float4*)(pl + p0 + 4);
                float2 C = *(const float2*)(pl + p0 + 8);
                c[q][0]=A.x; c[q][1]=A.y; c[q][2]=A.z; c[q][3]=A.w;
                c[q][4]=B.x; c[q][5]=B.y; c[q][6]=B.z; c[q][7]=B.w;
                c[q][8]=C.x; c[q][9]=C.y;
            }
            float W[5];
#pragma unroll
            for (int q = 0; q < 5; ++q)
                W[q] = ((c[q][0] + c[q][1]) + (c[q][2] + c[q][3])) +
                       ((c[q][4] + c[q][5]) + c[q][6]);
            accS += (p0 < OUTW) ? ssim_raw(W[0],W[1],W[2],W[3],W[4]) : 0.0f;
#pragma unroll
            for (int m = 1; m < 4; ++m) {
#pragma unroll
                for (int q = 0; q < 5; ++q)
                    W[q] += c[q][m + 6] - c[q][m - 1];
                float Sv = ssim_raw(W[0],W[1],W[2],W[3],W[4]);
                accS += (p0 + m < OUTW) ? Sv : 0.0f;
            }
        }
        __syncthreads();   // reads done before next iteration's writes
    }

    // block reduce -> one partial per block (no atomics, no init needed)
#pragma unroll
    for (int o = 32; o > 0; o >>= 1)
        accS += __shfl_down(accS, o, 64);
    if ((t & 63) == 0) wsum[t >> 6] = accS;
    __syncthreads();
    if (t == 0)
        partials[blockIdx.y * NBANDS + blockIdx.x] =
            (wsum[0] + wsum[1]) + (wsum[2] + wsum[3]);
}

__global__ __launch_bounds__(256) void ssim_finalize(const float* __restrict__ partials,
                                                     float* __restrict__ out) {
    __shared__ float wsum[4];
    const int t = threadIdx.x;
    float v = 0.0f;
    for (int i = t; i < NPART; i += 256) v += partials[i];
#pragma unroll
    for (int o = 32; o > 0; o >>= 1)
        v += __shfl_down(v, o, 64);
    if ((t & 63) == 0) wsum[t >> 6] = v;
    __syncthreads();
    if (t == 0)
        out[0] = 1.0f - ((wsum[0] + wsum[1]) + (wsum[2] + wsum[3])) / TOTAL_OUT;
}

extern "C" void kernel_launch(void* const* d_in, const int* in_sizes, int n_in,
                              void* d_out, int out_size, void* d_ws, size_t ws_size,
                              hipStream_t stream) {
    const float* X = (const float*)d_in[0];
    const float* Y = (const float*)d_in[1];
    float* partials = (float*)d_ws;          // NPART floats (8.8 KB)
    float* out = (float*)d_out;

    hipLaunchKernelGGL(ssim_main, dim3(NBANDS, NIMG), dim3(256), 0, stream,
                       X, Y, partials);
    hipLaunchKernelGGL(ssim_finalize, dim3(1), dim3(256), 0, stream,
                       partials, out);
}